// Round 14
// baseline (90.017 us; speedup 1.0000x reference)
//
#include <hip/hip_runtime.h>
#include <hip/hip_bf16.h>

#define N 8192
#define D 256
#define NSLICE 32
#define BM 128                          // rows per block (4 waves x 32 rows)
#define TROWS 2                         // row-tiles of 16 per wave
#define CB 32                           // cols per staged LDS tile
#define COLS_PER_SLICE (N / NSLICE)     // 256
#define NT (COLS_PER_SLICE / CB)        // 8 tiles per block
#define NRB (N / BM)                    // 64 row blocks
#define TILE_B (CB * D)                 // 8192 bytes per fp8 tile

#define CSHIFT 160.0f                   // fixed base-2 LSE shift
#define K2LOG2E 2.885390082f            // (1/T) * log2(e) = 2 * 1.44269504
#define LN2F 0.6931471805599453f

typedef __attribute__((ext_vector_type(4))) float f32x4;

__device__ inline float fast_exp2(float x) { return __builtin_amdgcn_exp2f(x); }
__device__ inline float fast_log2(float x) { return __builtin_amdgcn_logf(x); }

// async global->LDS, 16B per lane; LDS dest = wave-uniform base + lane*16.
__device__ inline void gload_lds16(const void* g, void* l) {
    __builtin_amdgcn_global_load_lds(
        (const __attribute__((address_space(1))) void*)g,
        (__attribute__((address_space(3))) void*)l, 16, 0, 0);
}

// pack 4 fp32 -> 4 fp8 e4m3 bytes (OCP on gfx950)
__device__ inline unsigned int pack_fp8x4(float a, float b, float c, float d) {
    unsigned int p = __builtin_amdgcn_cvt_pk_fp8_f32(a, b, 0, 0);    // bytes 0-1
    p = __builtin_amdgcn_cvt_pk_fp8_f32(c, d, (int)p, 1);            // bytes 2-3
    return p;
}

// ---------------- kernel 0: fp32 -> fp8 conversion + fused label histogram ----------------
// y==0: F row-major fp8; first 32 x-blocks also histogram the 8192 labels
//       (counts pre-zeroed via hipMemsetAsync; global atomics, 14 bins).
// y==1: I in FRAGMENT order so global_load_lds with LINEAR dest yields the
//       MFMA B-fragment layout (pre-swizzled global source pattern).
__global__ void convert_fp8(const float* __restrict__ F, const float* __restrict__ Imp,
                            unsigned int* __restrict__ Fb8, unsigned int* __restrict__ Ib8,
                            const int* __restrict__ labels, int* __restrict__ counts) {
    const int i = blockIdx.x * blockDim.x + threadIdx.x;  // 8 bytes per thread
    if (blockIdx.y == 0) {
        const float4 v0 = reinterpret_cast<const float4*>(F)[i * 2];
        const float4 v1 = reinterpret_cast<const float4*>(F)[i * 2 + 1];
        Fb8[i * 2] = pack_fp8x4(v0.x, v0.y, v0.z, v0.w);
        Fb8[i * 2 + 1] = pack_fp8x4(v1.x, v1.y, v1.z, v1.w);
        if (blockIdx.x < 32) atomicAdd(&counts[labels[i]], 1);  // i < 8192 here
    } else {
        const int lane = i & 63;
        const int ks = (i >> 6) & 7;
        const int g = i >> 9;
        const int col = g * 16 + (lane & 15);
        const int k0 = ks * 32 + (lane >> 4) * 8;
        const float* src = Imp + (size_t)col * D + k0;
        const float4 v0 = *reinterpret_cast<const float4*>(src);
        const float4 v1 = *reinterpret_cast<const float4*>(src + 4);
        Ib8[i * 2] = pack_fp8x4(v0.x, v0.y, v0.z, v0.w);
        Ib8[i * 2 + 1] = pack_fp8x4(v1.x, v1.y, v1.z, v1.w);
    }
}

// ---------------- kernel 1: fp8 single-pass tile kernel ----------------
// TLP round: LDS 21.5KB (double-buffer 2x8KB + colacc 4KB + labs 1KB) ->
// 7 blocks/CU resident (VGPR 52 <= 64 allows 8 waves/SIMD); grid 2048.
// Single vmcnt(0)+s_barrier per tile: the drain stall is covered by the
// 6 other resident blocks (r9's schedule failed only at 2 blocks/CU).
// blockIdx.x: row block (128 rows), blockIdx.y: column slice (256 cols).
__launch_bounds__(256, 8)
__global__ void tile_pass(const unsigned char* __restrict__ Fb8,
                          const unsigned char* __restrict__ Ib8,
                          const int* __restrict__ labels,
                          float* __restrict__ partials_row,    // [N][NSLICE]
                          float* __restrict__ partials_col) {  // [NRB][N]
    __shared__ __align__(16) unsigned char Bsh[2 * TILE_B];  // 16KB
    __shared__ float colacc[4][COLS_PER_SLICE];              // 4KB
    __shared__ int labs[COLS_PER_SLICE];                     // 1KB

    const int tid = threadIdx.x;
    const int lane = tid & 63;
    const int wave = tid >> 6;
    const int rb = blockIdx.x;
    const int row0 = rb * BM + wave * (16 * TROWS);
    const int c0 = blockIdx.y * COLS_PER_SLICE;
    const int lrow = lane & 15;
    const int kgrp = lane >> 4;

    // stage one 32-col tile (8KB, fragment-ordered in GLOBAL memory):
    // 8 chunks of 1KB; wave w stages chunks 2w, 2w+1; linear dest & src.
#define STAGE(buf, ct)                                                          \
    {                                                                           \
        const unsigned char* tbase = Ib8 + (size_t)(c0 + (ct) * CB) * D;        \
        _Pragma("unroll")                                                       \
        for (int i = 0; i < 2; ++i) {                                           \
            const int chunk = wave * 2 + i;                                     \
            gload_lds16(tbase + chunk * 1024 + lane * 16,                       \
                        &Bsh[(buf) * TILE_B + chunk * 1024 + lane * 16]);       \
        }                                                                       \
    }

    STAGE(0, 0);

    for (int i = tid; i < COLS_PER_SLICE; i += 256) {
        labs[i] = labels[c0 + i];
        colacc[0][i] = 0.f; colacc[1][i] = 0.f; colacc[2][i] = 0.f; colacc[3][i] = 0.f;
    }

    // A fragments fp8: 8 bytes/lane per (t,ks) = 2 VGPRs; 32 regs of data.
    long afrag[TROWS][8];
#pragma unroll
    for (int t = 0; t < TROWS; ++t) {
        const unsigned char* arow = Fb8 + (size_t)(row0 + t * 16 + lrow) * D;
#pragma unroll
        for (int ks = 0; ks < 8; ++ks)
            afrag[t][ks] = *reinterpret_cast<const long*>(arow + ks * 32 + kgrp * 8);
    }

    // my output rows' labels
    int labr[TROWS][4];
#pragma unroll
    for (int t = 0; t < TROWS; ++t) {
        const int base = row0 + t * 16 + kgrp * 4;
#pragma unroll
        for (int r = 0; r < 4; ++r) labr[t][r] = labels[base + r];
    }

    float s[TROWS][4];
#pragma unroll
    for (int t = 0; t < TROWS; ++t)
#pragma unroll
        for (int r = 0; r < 4; ++r) s[t][r] = 0.0f;

    // tile 0 landed; labs/colacc visible
    asm volatile("s_waitcnt vmcnt(0) lgkmcnt(0)" ::: "memory");
    __builtin_amdgcn_s_barrier();

    int cur = 0;
    for (int ct = 0; ct < NT; ++ct) {
        if (ct + 1 < NT) STAGE(cur ^ 1, ct + 1);  // prefetch next tile

        __builtin_amdgcn_s_setprio(1);
#pragma unroll
        for (int u = 0; u < 2; ++u) {
            long bfrag[8];
#pragma unroll
            for (int ks = 0; ks < 8; ++ks)
                bfrag[ks] = *reinterpret_cast<const long*>(
                    &Bsh[cur * TILE_B + (u * 8 + ks) * 512 + lane * 8]);  // linear

            const int labc = labs[ct * CB + u * 16 + lrow];
            float colpart = 0.0f;
            f32x4 acc[TROWS];
#pragma unroll
            for (int t = 0; t < TROWS; ++t) acc[t] = f32x4{0.f, 0.f, 0.f, 0.f};
#pragma unroll
            for (int ks = 0; ks < 8; ++ks)
#pragma unroll
                for (int t = 0; t < TROWS; ++t)
                    acc[t] = __builtin_amdgcn_mfma_f32_16x16x32_fp8_fp8(
                        afrag[t][ks], bfrag[ks], acc[t], 0, 0, 0);

#pragma unroll
            for (int t = 0; t < TROWS; ++t) {
                // D layout: col = lane&15, row = (lane>>4)*4 + r (dtype-indep)
#pragma unroll
                for (int r = 0; r < 4; ++r) {
                    float arg = __builtin_fmaf(acc[t][r], K2LOG2E, -CSHIFT);
                    arg = (labr[t][r] == labc) ? -1000.0f : arg;  // masked (incl. diag) -> 0
                    float e = fast_exp2(arg);
                    s[t][r] += e;
                    colpart += e;
                }
            }
            colpart += __shfl_xor(colpart, 16, 64);
            colpart += __shfl_xor(colpart, 32, 64);
            if (kgrp == 0)
                colacc[wave][ct * CB + u * 16 + lrow] += colpart;
        }
        __builtin_amdgcn_s_setprio(0);

        // single barrier per tile: my stage landed, my reads consumed
        asm volatile("s_waitcnt vmcnt(0)" ::: "memory");
        __builtin_amdgcn_s_barrier();
        cur ^= 1;
    }

    // row partials: sum the 16 lrow-lanes (disjoint column subsets)
#pragma unroll
    for (int off = 1; off < 16; off <<= 1) {
#pragma unroll
        for (int t = 0; t < TROWS; ++t)
#pragma unroll
            for (int r = 0; r < 4; ++r)
                s[t][r] += __shfl_xor(s[t][r], off, 64);
    }
    if (lrow == 0) {
#pragma unroll
        for (int t = 0; t < TROWS; ++t)
#pragma unroll
            for (int r = 0; r < 4; ++r) {
                const int grow = row0 + t * 16 + kgrp * 4 + r;
                partials_row[(size_t)grow * NSLICE + blockIdx.y] = s[t][r];
            }
    }

    __syncthreads();  // all colacc writes visible
    for (int i = tid; i < COLS_PER_SLICE; i += 256) {
        float v = colacc[0][i] + colacc[1][i] + colacc[2][i] + colacc[3][i];
        partials_col[(size_t)rb * N + c0 + i] = v;
    }
#undef STAGE
}

// ---------------- kernel 1b: reduce col partials over row blocks ----------------
__global__ void col_reduce(const float* __restrict__ partials_col, float* __restrict__ colsum) {
    const int c = blockIdx.x * 256 + threadIdx.x;
    float v = 0.0f;
    for (int rbi = 0; rbi < NRB; ++rbi) v += partials_col[(size_t)rbi * N + c];
    colsum[c] = v;
}

// exact lse over { S*2^CSHIFT (bulk), cnt*exp(0), exp(diag) }
__device__ inline float final_lse(float S, float cntlog, float diag) {
    float l1 = (S > 0.0f) ? (CSHIFT + fast_log2(S)) * LN2F : -INFINITY;
    float M = fmaxf(fmaxf(l1, cntlog), diag);  // M finite: diag always finite
    return M + __logf(__expf(l1 - M) + __expf(cntlog - M) + __expf(diag - M));
}

// ---------------- kernel 2: per-row contribution (wave per row) ----------------
__global__ void row_contrib(const float* __restrict__ F, const float* __restrict__ Imp,
                            const float* __restrict__ partials_row,
                            const float* __restrict__ colsum,
                            const int* __restrict__ counts,
                            const int* __restrict__ labels, float* __restrict__ blockSums) {
    const int lane = threadIdx.x & 63;
    const int wave = threadIdx.x >> 6;
    const int row = blockIdx.x * 4 + wave;

    // fp32 diagonal dot: 256 floats = 64 lanes * float4
    float4 a = reinterpret_cast<const float4*>(F + (size_t)row * D)[lane];
    float4 b = reinterpret_cast<const float4*>(Imp + (size_t)row * D)[lane];
    float dot = a.x * b.x + a.y * b.y + a.z * b.z + a.w * b.w;
#pragma unroll
    for (int off = 32; off > 0; off >>= 1) dot += __shfl_xor(dot, off, 64);

    // S_row: NSLICE partials in lanes 0..NSLICE-1 (zeros elsewhere)
    float sr = (lane < NSLICE) ? partials_row[(size_t)row * NSLICE + lane] : 0.0f;
#pragma unroll
    for (int off = 16; off > 0; off >>= 1) sr += __shfl_xor(sr, off, 64);

    __shared__ float sums[4];
    if (lane == 0) {
        const float diag = 2.0f * dot;                 // temperature 0.5
        const int cnt = counts[labels[row]] - 1;       // equal-label count excl. self
        const float cntlog = (cnt > 0) ? __logf((float)cnt) : -INFINITY;
        const float S_col = colsum[row];
        const float lse_total = final_lse(sr, cntlog, diag) + final_lse(S_col, cntlog, diag);
        sums[wave] = 2.0f * diag - lse_total;
    }
    __syncthreads();
    if (threadIdx.x == 0)
        blockSums[blockIdx.x] = sums[0] + sums[1] + sums[2] + sums[3];
}

// ---------------- kernel 3: final deterministic reduce ----------------
__global__ void final_reduce(const float* __restrict__ blockSums, float* __restrict__ out) {
    __shared__ float red[256];
    float v = 0.0f;
    for (int i = threadIdx.x; i < N / 4; i += 256) v += blockSums[i];
    red[threadIdx.x] = v;
    __syncthreads();
    for (int st = 128; st > 0; st >>= 1) {
        if (threadIdx.x < st) red[threadIdx.x] += red[threadIdx.x + st];
        __syncthreads();
    }
    if (threadIdx.x == 0) out[0] = -red[0] / (float)N;
}

extern "C" void kernel_launch(void* const* d_in, const int* in_sizes, int n_in,
                              void* d_out, int out_size, void* d_ws, size_t ws_size,
                              hipStream_t stream) {
    const float* F = (const float*)d_in[0];
    const float* Imp = (const float*)d_in[1];
    const int* labels = (const int*)d_in[2];
    float* out = (float*)d_out;

    char* ws = (char*)d_ws;
    size_t off = 0;
    unsigned char* Fb8 = (unsigned char*)(ws + off); off += (size_t)N * D;    // 2 MB
    unsigned char* Ib8 = (unsigned char*)(ws + off); off += (size_t)N * D;    // 2 MB
    float* partials_row = (float*)(ws + off); off += (size_t)N * NSLICE * 4;  // 1 MB
    float* partials_col = (float*)(ws + off); off += (size_t)NRB * N * 4;     // 2 MB
    float* colsum = (float*)(ws + off); off += (size_t)N * 4;                 // 32 KB
    float* blockSums = (float*)(ws + off); off += (size_t)(N / 4) * 4;        // 8 KB
    int* counts = (int*)(ws + off);

    hipMemsetAsync(counts, 0, 16 * sizeof(int), stream);

    dim3 cgrid(N * D / 8 / 256, 2);  // 8 bytes per thread
    convert_fp8<<<cgrid, 256, 0, stream>>>(F, Imp, (unsigned int*)Fb8, (unsigned int*)Ib8,
                                           labels, counts);

    dim3 g(NRB, NSLICE);
    tile_pass<<<g, 256, 0, stream>>>(Fb8, Ib8, labels, partials_row, partials_col);

    col_reduce<<<N / 256, 256, 0, stream>>>(partials_col, colsum);
    row_contrib<<<N / 4, 256, 0, stream>>>(F, Imp, partials_row, colsum, counts, labels, blockSums);
    final_reduce<<<1, 256, 0, stream>>>(blockSums, out);
}

// Round 15
// 60.071 us; speedup vs baseline: 1.4985x; 1.4985x over previous
//
#include <hip/hip_runtime.h>
#include <hip/hip_bf16.h>

#define N 8192
#define D 256
#define NSLICE 32
#define BM 256                          // rows per block (4 waves x 64 rows)
#define TROWS 4                         // row-tiles of 16 per wave
#define COLS_PER_SLICE (N / NSLICE)     // 256
#define NSTRIP (COLS_PER_SLICE / 16)    // 16 strips of 16 cols
#define NRB (N / BM)                    // 32 row blocks

#define CSHIFT 160.0f                   // fixed base-2 LSE shift
#define K2LOG2E 2.885390082f            // (1/T) * log2(e) = 2 * 1.44269504
#define LN2F 0.6931471805599453f

typedef __attribute__((ext_vector_type(4))) float f32x4;

__device__ inline float fast_exp2(float x) { return __builtin_amdgcn_exp2f(x); }
__device__ inline float fast_log2(float x) { return __builtin_amdgcn_logf(x); }

// pack 4 fp32 -> 4 fp8 e4m3 bytes (OCP on gfx950)
__device__ inline unsigned int pack_fp8x4(float a, float b, float c, float d) {
    unsigned int p = __builtin_amdgcn_cvt_pk_fp8_f32(a, b, 0, 0);    // bytes 0-1
    p = __builtin_amdgcn_cvt_pk_fp8_f32(c, d, (int)p, 1);            // bytes 2-3
    return p;
}

// ---------------- kernel 0: fp32 -> fp8, BOTH in fragment order ----------------
// 16-row group g, slice ks, lane l (8B per thread):
//   byte i*8 = g*4096 + ks*512 + l*8  holds  X[g*16 + (l&15)][ks*32 + (l>>4)*8 .. +7]
// -> per-(tile,ks) fragment loads in tile_pass are single coalesced b64 reads.
__global__ void convert_fp8(const float* __restrict__ F, const float* __restrict__ Imp,
                            unsigned int* __restrict__ Fb8, unsigned int* __restrict__ Ib8) {
    const int i = blockIdx.x * blockDim.x + threadIdx.x;  // 8 bytes per thread
    const float* src = (blockIdx.y == 0) ? F : Imp;
    unsigned int* dst = (blockIdx.y == 0) ? Fb8 : Ib8;
    const int l = i & 63;
    const int ks = (i >> 6) & 7;
    const int g = i >> 9;
    const int row = g * 16 + (l & 15);
    const int k0 = ks * 32 + (l >> 4) * 8;
    const float* p = src + (size_t)row * D + k0;
    const float4 v0 = *reinterpret_cast<const float4*>(p);
    const float4 v1 = *reinterpret_cast<const float4*>(p + 4);
    dst[i * 2] = pack_fp8x4(v0.x, v0.y, v0.z, v0.w);
    dst[i * 2 + 1] = pack_fp8x4(v1.x, v1.y, v1.z, v1.w);
}

// ---------------- kernel 0b: label histogram (14 bins) ----------------
__global__ void label_hist(const int* __restrict__ labels, int* __restrict__ counts) {
    __shared__ int c[16];
    if (threadIdx.x < 16) c[threadIdx.x] = 0;
    __syncthreads();
    for (int i = threadIdx.x; i < N; i += blockDim.x) atomicAdd(&c[labels[i]], 1);
    __syncthreads();
    if (threadIdx.x < 16) counts[threadIdx.x] = c[threadIdx.x];
}

// ---------------- kernel 1: free-running register-streaming fp8 kernel ----------------
// NO B LDS staging, NO main-loop barriers: each wave streams its B fragments
// straight from L2 into a register double-buffer and free-runs (r12-r14 showed
// the lockstep vmcnt-drain+barrier per tile is the cost; A lives in AGPRs).
// 64 rows/wave (TROWS=4) halves B traffic vs 32 rows: 256MB L2 reads total.
// LDS only for labs + per-wave colacc (5KB) -> occupancy reg-capped ~3 w/SIMD.
// blockIdx.x: row block (256 rows), blockIdx.y: column slice (256 cols).
__launch_bounds__(256, 2)
__global__ void tile_pass(const unsigned char* __restrict__ Fb8,
                          const unsigned char* __restrict__ Ib8,
                          const int* __restrict__ labels,
                          float* __restrict__ partials_row,    // [N][NSLICE]
                          float* __restrict__ partials_col) {  // [NRB][N]
    __shared__ float colacc[4][COLS_PER_SLICE];   // 4KB, per-wave private
    __shared__ int labs[COLS_PER_SLICE];          // 1KB

    const int tid = threadIdx.x;
    const int lane = tid & 63;
    const int wave = tid >> 6;
    const int rb = blockIdx.x;
    const int row0 = rb * BM + wave * (16 * TROWS);
    const int rg0 = row0 >> 4;                    // A row-group index
    const int c0 = blockIdx.y * COLS_PER_SLICE;
    const int cg0 = c0 >> 4;                      // B col-group index
    const int lrow = lane & 15;
    const int kgrp = lane >> 4;

    for (int i = tid; i < COLS_PER_SLICE; i += 256) {
        labs[i] = labels[c0 + i];
        colacc[0][i] = 0.f; colacc[1][i] = 0.f; colacc[2][i] = 0.f; colacc[3][i] = 0.f;
    }

    // A fragments (fragment-ordered global): coalesced b64 per (t,ks)
    long afrag[TROWS][8];
#pragma unroll
    for (int t = 0; t < TROWS; ++t)
#pragma unroll
        for (int ks = 0; ks < 8; ++ks)
            afrag[t][ks] = *reinterpret_cast<const long*>(
                Fb8 + (size_t)(rg0 + t) * 4096 + ks * 512 + lane * 8);

    int labr[TROWS][4];
#pragma unroll
    for (int t = 0; t < TROWS; ++t) {
        const int base = row0 + t * 16 + kgrp * 4;
#pragma unroll
        for (int r = 0; r < 4; ++r) labr[t][r] = labels[base + r];
    }

    float s[TROWS][4];
#pragma unroll
    for (int t = 0; t < TROWS; ++t)
#pragma unroll
        for (int r = 0; r < 4; ++r) s[t][r] = 0.0f;

    __syncthreads();  // labs/colacc ready — the ONLY pre-epilogue barrier

#define LOADB(buf, st)                                                          \
    {                                                                           \
        const unsigned char* sb = Ib8 + (size_t)(cg0 + (st)) * 4096 + lane * 8; \
        _Pragma("unroll")                                                       \
        for (int ks = 0; ks < 8; ++ks)                                          \
            buf[ks] = *reinterpret_cast<const long*>(sb + ks * 512);            \
    }

#define COMPUTE(buf, st)                                                        \
    {                                                                           \
        const int labc = labs[(st) * 16 + lrow];                                \
        f32x4 acc[TROWS];                                                       \
        _Pragma("unroll")                                                       \
        for (int t = 0; t < TROWS; ++t) acc[t] = f32x4{0.f, 0.f, 0.f, 0.f};     \
        __builtin_amdgcn_s_setprio(1);                                          \
        _Pragma("unroll")                                                       \
        for (int ks = 0; ks < 8; ++ks)                                          \
            _Pragma("unroll")                                                   \
            for (int t = 0; t < TROWS; ++t)                                     \
                acc[t] = __builtin_amdgcn_mfma_f32_16x16x32_fp8_fp8(            \
                    afrag[t][ks], buf[ks], acc[t], 0, 0, 0);                    \
        __builtin_amdgcn_s_setprio(0);                                          \
        float colpart = 0.0f;                                                   \
        _Pragma("unroll")                                                       \
        for (int t = 0; t < TROWS; ++t) {                                       \
            _Pragma("unroll")                                                   \
            for (int r = 0; r < 4; ++r) {                                       \
                float arg = __builtin_fmaf(acc[t][r], K2LOG2E, -CSHIFT);        \
                arg = (labr[t][r] == labc) ? -1000.0f : arg;                    \
                float e = fast_exp2(arg);                                       \
                s[t][r] += e;                                                   \
                colpart += e;                                                   \
            }                                                                   \
        }                                                                       \
        colpart += __shfl_xor(colpart, 16, 64);                                 \
        colpart += __shfl_xor(colpart, 32, 64);                                 \
        if (kgrp == 0) colacc[wave][(st) * 16 + lrow] += colpart;               \
    }

    // register double-buffer, manual 2-step body (static indexing, rule #20)
    long bA[8], bB[8];
    LOADB(bA, 0);
#pragma unroll 1
    for (int st = 0; st < NSTRIP; st += 2) {
        LOADB(bB, st + 1);                       // NSTRIP even
        COMPUTE(bA, st);
        if (st + 2 < NSTRIP) LOADB(bA, st + 2);
        COMPUTE(bB, st + 1);
    }
#undef LOADB
#undef COMPUTE

    // row partials: sum the 16 lrow-lanes (disjoint column subsets)
#pragma unroll
    for (int off = 1; off < 16; off <<= 1) {
#pragma unroll
        for (int t = 0; t < TROWS; ++t)
#pragma unroll
            for (int r = 0; r < 4; ++r)
                s[t][r] += __shfl_xor(s[t][r], off, 64);
    }
    if (lrow == 0) {
#pragma unroll
        for (int t = 0; t < TROWS; ++t)
#pragma unroll
            for (int r = 0; r < 4; ++r) {
                const int grow = row0 + t * 16 + kgrp * 4 + r;
                partials_row[(size_t)grow * NSLICE + blockIdx.y] = s[t][r];
            }
    }

    __syncthreads();  // all colacc writes visible
    for (int i = tid; i < COLS_PER_SLICE; i += 256) {
        float v = colacc[0][i] + colacc[1][i] + colacc[2][i] + colacc[3][i];
        partials_col[(size_t)rb * N + c0 + i] = v;
    }
}

// ---------------- kernel 1b: reduce col partials over row blocks ----------------
__global__ void col_reduce(const float* __restrict__ partials_col, float* __restrict__ colsum) {
    const int c = blockIdx.x * 256 + threadIdx.x;
    float v = 0.0f;
    for (int rbi = 0; rbi < NRB; ++rbi) v += partials_col[(size_t)rbi * N + c];
    colsum[c] = v;
}

// exact lse over { S*2^CSHIFT (bulk), cnt*exp(0), exp(diag) }
__device__ inline float final_lse(float S, float cntlog, float diag) {
    float l1 = (S > 0.0f) ? (CSHIFT + fast_log2(S)) * LN2F : -INFINITY;
    float M = fmaxf(fmaxf(l1, cntlog), diag);  // M finite: diag always finite
    return M + __logf(__expf(l1 - M) + __expf(cntlog - M) + __expf(diag - M));
}

// ---------------- kernel 2: per-row contribution (wave per row) ----------------
__global__ void row_contrib(const float* __restrict__ F, const float* __restrict__ Imp,
                            const float* __restrict__ partials_row,
                            const float* __restrict__ colsum,
                            const int* __restrict__ counts,
                            const int* __restrict__ labels, float* __restrict__ blockSums) {
    const int lane = threadIdx.x & 63;
    const int wave = threadIdx.x >> 6;
    const int row = blockIdx.x * 4 + wave;

    // fp32 diagonal dot: 256 floats = 64 lanes * float4
    float4 a = reinterpret_cast<const float4*>(F + (size_t)row * D)[lane];
    float4 b = reinterpret_cast<const float4*>(Imp + (size_t)row * D)[lane];
    float dot = a.x * b.x + a.y * b.y + a.z * b.z + a.w * b.w;
#pragma unroll
    for (int off = 32; off > 0; off >>= 1) dot += __shfl_xor(dot, off, 64);

    // S_row: NSLICE partials in lanes 0..NSLICE-1 (zeros elsewhere)
    float sr = (lane < NSLICE) ? partials_row[(size_t)row * NSLICE + lane] : 0.0f;
#pragma unroll
    for (int off = 16; off > 0; off >>= 1) sr += __shfl_xor(sr, off, 64);

    __shared__ float sums[4];
    if (lane == 0) {
        const float diag = 2.0f * dot;                 // temperature 0.5
        const int cnt = counts[labels[row]] - 1;       // equal-label count excl. self
        const float cntlog = (cnt > 0) ? __logf((float)cnt) : -INFINITY;
        const float S_col = colsum[row];
        const float lse_total = final_lse(sr, cntlog, diag) + final_lse(S_col, cntlog, diag);
        sums[wave] = 2.0f * diag - lse_total;
    }
    __syncthreads();
    if (threadIdx.x == 0)
        blockSums[blockIdx.x] = sums[0] + sums[1] + sums[2] + sums[3];
}

// ---------------- kernel 3: final deterministic reduce ----------------
__global__ void final_reduce(const float* __restrict__ blockSums, float* __restrict__ out) {
    __shared__ float red[256];
    float v = 0.0f;
    for (int i = threadIdx.x; i < N / 4; i += 256) v += blockSums[i];
    red[threadIdx.x] = v;
    __syncthreads();
    for (int st = 128; st > 0; st >>= 1) {
        if (threadIdx.x < st) red[threadIdx.x] += red[threadIdx.x + st];
        __syncthreads();
    }
    if (threadIdx.x == 0) out[0] = -red[0] / (float)N;
}

extern "C" void kernel_launch(void* const* d_in, const int* in_sizes, int n_in,
                              void* d_out, int out_size, void* d_ws, size_t ws_size,
                              hipStream_t stream) {
    const float* F = (const float*)d_in[0];
    const float* Imp = (const float*)d_in[1];
    const int* labels = (const int*)d_in[2];
    float* out = (float*)d_out;

    char* ws = (char*)d_ws;
    size_t off = 0;
    unsigned char* Fb8 = (unsigned char*)(ws + off); off += (size_t)N * D;    // 2 MB
    unsigned char* Ib8 = (unsigned char*)(ws + off); off += (size_t)N * D;    // 2 MB
    float* partials_row = (float*)(ws + off); off += (size_t)N * NSLICE * 4;  // 1 MB
    float* partials_col = (float*)(ws + off); off += (size_t)NRB * N * 4;     // 1 MB
    float* colsum = (float*)(ws + off); off += (size_t)N * 4;                 // 32 KB
    float* blockSums = (float*)(ws + off); off += (size_t)(N / 4) * 4;        // 8 KB
    int* counts = (int*)(ws + off);

    dim3 cgrid(N * D / 8 / 256, 2);  // 8 bytes per thread
    convert_fp8<<<cgrid, 256, 0, stream>>>(F, Imp, (unsigned int*)Fb8, (unsigned int*)Ib8);
    label_hist<<<1, 256, 0, stream>>>(labels, counts);

    dim3 g(NRB, NSLICE);
    tile_pass<<<g, 256, 0, stream>>>(Fb8, Ib8, labels, partials_row, partials_col);

    col_reduce<<<N / 256, 256, 0, stream>>>(partials_col, colsum);
    row_contrib<<<N / 4, 256, 0, stream>>>(F, Imp, partials_row, colsum, counts, labels, blockSums);
    final_reduce<<<1, 256, 0, stream>>>(blockSums, out);
}